// Round 3
// baseline (119.728 us; speedup 1.0000x reference)
//
#include <hip/hip_runtime.h>
#include <hip/hip_bf16.h>
#include <math.h>

#define B_     32
#define HID_   768
#define OUT5_  2304
#define HDIM_  512
#define NC_    65536
#define MAXG_  11
#define NL_    670091
#define TOPK_  10
#define CAND_  110   // TOPK_*MAXG_
#define NOUT_  3520  // B_*CAND_
#define NSTRIPE_ 512 // meta col stripes (65536/128)

__device__ __forceinline__ float gelu_exact(float x){
  return 0.5f * x * (1.0f + erff(x * 0.70710678118654752440f));
}

__device__ __forceinline__ unsigned long long packv(float x, int col){
  unsigned u = __float_as_uint(x);
  u = (u & 0x80000000u) ? ~u : (u | 0x80000000u);   // order-preserving float->uint
  return (((unsigned long long)u) << 16) | (unsigned long long)(65535 - col); // tie -> lower col wins
}

__device__ __forceinline__ float unpack_val(unsigned long long g){
  unsigned u = (unsigned)(g >> 16);
  unsigned bits = (u & 0x80000000u) ? (u & 0x7FFFFFFFu) : ~u;
  return __uint_as_float(bits);
}

__device__ __forceinline__ int unpack_col(unsigned long long g){
  return 65535 - (int)(g & 0xFFFFULL);
}

__device__ __forceinline__ unsigned long long wave_max_u64(unsigned long long m){
  #pragma unroll
  for (int off = 1; off < 64; off <<= 1){
    unsigned long long o = __shfl_xor(m, off);
    if (o > m) m = o;
  }
  return m;
}

__device__ __forceinline__ unsigned long long block_max_u64(unsigned long long m,
                                                            unsigned long long* sm, int nwaves){
  m = wave_max_u64(m);
  const int tid = threadIdx.x;
  if ((tid & 63) == 0) sm[tid >> 6] = m;
  __syncthreads();
  unsigned long long g = sm[0];
  for (int w = 1; w < nwaves; ++w) if (sm[w] > g) g = sm[w];
  __syncthreads();
  return g;
}

// K1: partial sums for the two small GEMMs (deterministic k-chunk split).
__global__ __launch_bounds__(256)
void mlp_partial(const float* __restrict__ hidf, const float* __restrict__ hidl5,
                 const float* __restrict__ W1, const float* __restrict__ Wext,
                 float* __restrict__ partial){
  const int jl  = threadIdx.x & 63;
  const int bq  = threadIdx.x >> 6;
  const int col = blockIdx.x * 64 + jl;
  const int chunk = blockIdx.y;
  const float* W; const float* X; int Kfull, k0;
  if (chunk < 4){ W = W1;   X = hidf;  Kfull = HID_;  k0 = chunk * 192; }
  else          { W = Wext; X = hidl5; Kfull = OUT5_; k0 = (chunk - 4) * 192; }
  const float* Wp = W + (size_t)k0 * HDIM_ + col;
  const float* Xp = X + (size_t)(bq * 8) * Kfull + k0;
  float acc[8] = {0,0,0,0,0,0,0,0};
  for (int k = 0; k < 192; ++k){
    float w = Wp[(size_t)k * HDIM_];
    #pragma unroll
    for (int i = 0; i < 8; ++i)
      acc[i] = fmaf(Xp[(size_t)i * Kfull + k], w, acc[i]);
  }
  float* outp = partial + (size_t)chunk * (B_ * HDIM_) + (size_t)(bq * 8) * HDIM_ + col;
  #pragma unroll
  for (int i = 0; i < 8; ++i) outp[(size_t)i * HDIM_] = acc[i];
}

// K2: reduce chunks + bias + exact GELU. hT transposed [HDIM][B] for K3.
__global__ __launch_bounds__(256)
void act_kernel(const float* __restrict__ partial, const float* __restrict__ b1,
                const float* __restrict__ bext, float* __restrict__ hT,
                float* __restrict__ h_ext){
  const int t = blockIdx.x * 256 + threadIdx.x;
  if (t < B_ * HDIM_){
    const int b = t >> 9, j = t & 511;
    float s = b1[j];
    #pragma unroll
    for (int c = 0; c < 4; ++c) s += partial[c * (B_ * HDIM_) + t];
    hT[j * B_ + b] = gelu_exact(s);
  } else {
    const int u = t - B_ * HDIM_;
    const int j = u & 511;
    float s = bext[j];
    #pragma unroll
    for (int c = 4; c < 16; ++c) s += partial[c * (B_ * HDIM_) + u];
    h_ext[u] = gelu_exact(s);
  }
}

// K3: meta GEMM + fused per-(row, 128-col stripe) top-10.  No logits materialization.
// 512 blocks x 256 thr; wave owns 8 rows x 128 cols (2 cols/lane).
__global__ __launch_bounds__(256)
void meta_topk(const float* __restrict__ hT, const float* __restrict__ W2,
               const float* __restrict__ b2, unsigned long long* __restrict__ segtop){
  const int lane = threadIdx.x & 63;
  const int bq   = threadIdx.x >> 6;
  const int col0 = blockIdx.x * 128 + lane * 2;
  const int sb8  = __builtin_amdgcn_readfirstlane(bq * 8);
  const float* __restrict__ hrow = hT + sb8;
  const float2* __restrict__ Wp = reinterpret_cast<const float2*>(W2) + (col0 >> 1);
  float acc[8][2];
  #pragma unroll
  for (int i = 0; i < 8; ++i){ acc[i][0] = 0.f; acc[i][1] = 0.f; }
  #pragma unroll 8
  for (int k = 0; k < HDIM_; ++k){
    float2 w  = Wp[(size_t)k * (NC_ / 2)];
    float4 h0 = *reinterpret_cast<const float4*>(hrow + (size_t)k * B_);
    float4 h1 = *reinterpret_cast<const float4*>(hrow + (size_t)k * B_ + 4);
    acc[0][0] = fmaf(h0.x, w.x, acc[0][0]); acc[0][1] = fmaf(h0.x, w.y, acc[0][1]);
    acc[1][0] = fmaf(h0.y, w.x, acc[1][0]); acc[1][1] = fmaf(h0.y, w.y, acc[1][1]);
    acc[2][0] = fmaf(h0.z, w.x, acc[2][0]); acc[2][1] = fmaf(h0.z, w.y, acc[2][1]);
    acc[3][0] = fmaf(h0.w, w.x, acc[3][0]); acc[3][1] = fmaf(h0.w, w.y, acc[3][1]);
    acc[4][0] = fmaf(h1.x, w.x, acc[4][0]); acc[4][1] = fmaf(h1.x, w.y, acc[4][1]);
    acc[5][0] = fmaf(h1.y, w.x, acc[5][0]); acc[5][1] = fmaf(h1.y, w.y, acc[5][1]);
    acc[6][0] = fmaf(h1.z, w.x, acc[6][0]); acc[6][1] = fmaf(h1.z, w.y, acc[6][1]);
    acc[7][0] = fmaf(h1.w, w.x, acc[7][0]); acc[7][1] = fmaf(h1.w, w.y, acc[7][1]);
  }
  const float2 bb = *reinterpret_cast<const float2*>(b2 + col0);
  #pragma unroll
  for (int r = 0; r < 8; ++r){
    unsigned long long p0 = packv(acc[r][0] + bb.x, col0);
    unsigned long long p1 = packv(acc[r][1] + bb.y, col0 + 1);
    unsigned long long g[10];
    #pragma unroll
    for (int rr = 0; rr < 10; ++rr){
      unsigned long long m = (p0 > p1) ? p0 : p1;
      m = wave_max_u64(m);                 // uniform winner
      g[rr] = m;
      if (p0 == m) p0 = 0ULL;
      else if (p1 == m) p1 = 0ULL;
    }
    unsigned long long sel = g[0];
    #pragma unroll
    for (int j = 1; j < 10; ++j) sel = (lane == j) ? g[j] : sel;
    if (lane < 10)
      segtop[((size_t)(sb8 + r) * NSTRIPE_ + blockIdx.x) * 10 + lane] = sel;
  }
}

// K4: merge 512 stripes x 10 -> global top-10 per row. 32 blocks x 256 thr.
__global__ __launch_bounds__(256)
void topk_merge(const unsigned long long* __restrict__ segtop,
                int* __restrict__ tk_idx, float* __restrict__ tk_score){
  __shared__ unsigned long long sm[4];
  const int row = blockIdx.x;
  const int tid = threadIdx.x;
  const unsigned long long* base = segtop + (size_t)row * (NSTRIPE_ * 10);
  unsigned long long v[10];
  #pragma unroll
  for (int r = 0; r < 10; ++r) v[r] = 0ULL;
  for (int i = 0; i < 20; ++i){
    const unsigned long long x = base[i * 256 + tid];
    if (x > v[9]){
      v[9] = x;
      #pragma unroll
      for (int p = 9; p > 0; --p){
        if (v[p] > v[p-1]){ unsigned long long t = v[p]; v[p] = v[p-1]; v[p-1] = t; }
      }
    }
  }
  for (int r = 0; r < 10; ++r){
    unsigned long long g = block_max_u64(v[0], sm, 4);
    if (v[0] == g && g != 0ULL){
      #pragma unroll
      for (int q = 0; q < 9; ++q) v[q] = v[q+1];
      v[9] = 0ULL;
    }
    if (tid == 0){
      tk_idx[row * TOPK_ + r]   = unpack_col(g);
      tk_score[row * TOPK_ + r] = 1.0f / (1.0f + expf(-unpack_val(g)));
    }
  }
}

// K5: candidate gather + dot + outputs. d_out: [cands f32][cscores bf16][comb bf16]
__global__ __launch_bounds__(256)
void cand_kernel(const int* __restrict__ gy, const float* __restrict__ embed,
                 const float* __restrict__ h_ext, const int* __restrict__ tk_idx,
                 const float* __restrict__ tk_score, float* __restrict__ out_f){
  const int wid  = threadIdx.x >> 6;
  const int lane = threadIdx.x & 63;
  const int gw   = blockIdx.x * 4 + wid;
  const int b    = gw / CAND_;
  const int c    = gw - b * CAND_;
  const int t    = c / MAXG_;
  const int g    = c - t * MAXG_;

  const unsigned int* gyw = (const unsigned int*)gy;
  const unsigned int probe = gyw[2 * (size_t)(gw * 64 + lane) + 1];
  const bool is64 = (__ballot(probe != 0u) == 0ULL);   // int64 vs int32 group_y layout

  const int idx  = tk_idx[b * TOPK_ + t];
  const size_t li = (size_t)idx * MAXG_ + g;
  const int cand = is64 ? (int)((const long long*)gy)[li] : gy[li];

  const float* erow = embed + (size_t)cand * HDIM_;
  const float* hrow = h_ext + (size_t)b * HDIM_;
  const float4 e0 = reinterpret_cast<const float4*>(erow)[lane];
  const float4 e1 = reinterpret_cast<const float4*>(erow)[lane + 64];
  const float4 h0 = reinterpret_cast<const float4*>(hrow)[lane];
  const float4 h1 = reinterpret_cast<const float4*>(hrow)[lane + 64];
  float s = e0.x*h0.x + e0.y*h0.y + e0.z*h0.z + e0.w*h0.w
          + e1.x*h1.x + e1.y*h1.y + e1.z*h1.z + e1.w*h1.w;
  #pragma unroll
  for (int off = 1; off < 64; off <<= 1) s += __shfl_xor(s, off);
  if (lane == 0){
    const float cs   = (s == 0.0f) ? 0.0f : 1.0f / (1.0f + expf(-s));
    const float comb = cs * ((cand != NL_) ? tk_score[b * TOPK_ + t] : 0.0f);
    const int o = b * CAND_ + c;
    __hip_bfloat16* outs = (__hip_bfloat16*)(out_f + NOUT_);
    __hip_bfloat16* outm = outs + NOUT_;
    out_f[o] = (float)cand;
    outs[o]  = __float2bfloat16(cs);
    outm[o]  = __float2bfloat16(comb);
  }
}

extern "C" void kernel_launch(void* const* d_in, const int* in_sizes, int n_in,
                              void* d_out, int out_size, void* d_ws, size_t ws_size,
                              hipStream_t stream){
  const float* hidf  = (const float*)d_in[0];
  const float* hidl5 = (const float*)d_in[1];
  const float* W1    = (const float*)d_in[2];
  const float* b1    = (const float*)d_in[3];
  const float* W2    = (const float*)d_in[4];
  const float* b2    = (const float*)d_in[5];
  const float* Wext  = (const float*)d_in[6];
  const float* bext  = (const float*)d_in[7];
  const float* embed = (const float*)d_in[8];
  const int*   gy    = (const int*)d_in[9];
  float* out_f = (float*)d_out;

  float* ws      = (float*)d_ws;
  float* partial = ws;                               // 16*16384 f32 (1 MiB)
  float* hT      = partial + 16 * (B_ * HDIM_);      // [512][32]
  float* h_ext   = hT + B_ * HDIM_;                  // [32][512]
  unsigned long long* segtop = (unsigned long long*)(h_ext + B_ * HDIM_); // [32][512][10] u64 (1.3 MB)
  float* tk_sc   = (float*)(segtop + (size_t)B_ * NSTRIPE_ * 10);         // 320
  int*   tk_ix   = (int*)(tk_sc + 320);                                   // 320

  mlp_partial<<<dim3(8, 16), 256, 0, stream>>>(hidf, hidl5, W1, Wext, partial);
  act_kernel <<<128, 256, 0, stream>>>(partial, b1, bext, hT, h_ext);
  meta_topk  <<<NSTRIPE_, 256, 0, stream>>>(hT, W2, b2, segtop);
  topk_merge <<<B_, 256, 0, stream>>>(segtop, tk_ix, tk_sc);
  cand_kernel<<<NOUT_ / 4, 256, 0, stream>>>(gy, embed, h_ext, tk_ix, tk_sc, out_f);
}

// Round 4
// 109.907 us; speedup vs baseline: 1.0894x; 1.0894x over previous
//
#include <hip/hip_runtime.h>
#include <hip/hip_bf16.h>
#include <math.h>

#define B_     32
#define HID_   768
#define OUT5_  2304
#define HDIM_  512
#define NC_    65536
#define MAXG_  11
#define NL_    670091
#define TOPK_  10
#define CAND_  110   // TOPK_*MAXG_
#define NOUT_  3520  // B_*CAND_

__device__ __forceinline__ float gelu_exact(float x){
  return 0.5f * x * (1.0f + erff(x * 0.70710678118654752440f));
}

__device__ __forceinline__ unsigned long long packv(float x, int col){
  unsigned u = __float_as_uint(x);
  u = (u & 0x80000000u) ? ~u : (u | 0x80000000u);   // order-preserving float->uint
  return (((unsigned long long)u) << 16) | (unsigned long long)(65535 - col); // tie -> lower col wins
}

__device__ __forceinline__ float unpack_val(unsigned long long g){
  unsigned u = (unsigned)(g >> 16);
  unsigned bits = (u & 0x80000000u) ? (u & 0x7FFFFFFFu) : ~u;
  return __uint_as_float(bits);
}

__device__ __forceinline__ int unpack_col(unsigned long long g){
  return 65535 - (int)(g & 0xFFFFULL);
}

__device__ __forceinline__ unsigned long long block_max_u64(unsigned long long m,
                                                            unsigned long long* sm, int nwaves){
  #pragma unroll
  for (int off = 1; off < 64; off <<= 1){
    unsigned long long o = __shfl_xor(m, off);
    if (o > m) m = o;
  }
  const int tid = threadIdx.x;
  if ((tid & 63) == 0) sm[tid >> 6] = m;
  __syncthreads();
  unsigned long long g = sm[0];
  for (int w = 1; w < nwaves; ++w) if (sm[w] > g) g = sm[w];
  __syncthreads();
  return g;
}

typedef const __attribute__((address_space(1))) void* gas_t;
typedef __attribute__((address_space(3))) void* las_t;
__device__ __forceinline__ void gload_lds16(const float* g, float* l){
  // HW semantics: LDS dest = wave-uniform base + lane*16; global src per-lane.
  __builtin_amdgcn_global_load_lds((gas_t)(const void*)g, (las_t)(void*)l, 16, 0, 0);
}

// K1: partial sums for the two small GEMMs (deterministic k-chunk split).
__global__ __launch_bounds__(256)
void mlp_partial(const float* __restrict__ hidf, const float* __restrict__ hidl5,
                 const float* __restrict__ W1, const float* __restrict__ Wext,
                 float* __restrict__ partial){
  const int jl  = threadIdx.x & 63;
  const int bq  = threadIdx.x >> 6;
  const int col = blockIdx.x * 64 + jl;
  const int chunk = blockIdx.y;
  const float* W; const float* X; int Kfull, k0;
  if (chunk < 4){ W = W1;   X = hidf;  Kfull = HID_;  k0 = chunk * 192; }
  else          { W = Wext; X = hidl5; Kfull = OUT5_; k0 = (chunk - 4) * 192; }
  const float* Wp = W + (size_t)k0 * HDIM_ + col;
  const float* Xp = X + (size_t)(bq * 8) * Kfull + k0;
  float acc[8] = {0,0,0,0,0,0,0,0};
  for (int k = 0; k < 192; ++k){
    float w = Wp[(size_t)k * HDIM_];
    #pragma unroll
    for (int i = 0; i < 8; ++i)
      acc[i] = fmaf(Xp[(size_t)i * Kfull + k], w, acc[i]);
  }
  float* outp = partial + (size_t)chunk * (B_ * HDIM_) + (size_t)(bq * 8) * HDIM_ + col;
  #pragma unroll
  for (int i = 0; i < 8; ++i) outp[(size_t)i * HDIM_] = acc[i];
}

// K2: reduce chunks + bias + exact GELU. hT transposed [HDIM][B] for K3.
__global__ __launch_bounds__(256)
void act_kernel(const float* __restrict__ partial, const float* __restrict__ b1,
                const float* __restrict__ bext, float* __restrict__ hT,
                float* __restrict__ h_ext){
  const int t = blockIdx.x * 256 + threadIdx.x;
  if (t < B_ * HDIM_){
    const int b = t >> 9, j = t & 511;
    float s = b1[j];
    #pragma unroll
    for (int c = 0; c < 4; ++c) s += partial[c * (B_ * HDIM_) + t];
    hT[j * B_ + b] = gelu_exact(s);
  } else {
    const int u = t - B_ * HDIM_;
    const int j = u & 511;
    float s = bext[j];
    #pragma unroll
    for (int c = 4; c < 16; ++c) s += partial[c * (B_ * HDIM_) + u];
    h_ext[u] = gelu_exact(s);
  }
}

// K3: meta GEMM with double-buffered LDS staging of W2 (each line fetched from
// HBM exactly once per block, barrier-synced so waves cannot drift).
// 512 blocks x 256 thr; block = 128-col stripe; wave bq -> 8 batch rows;
// lane owns cols (colBase+l) and (colBase+64+l).
#define CK_ 64
__global__ __launch_bounds__(256)
void meta_gemm(const float* __restrict__ hT, const float* __restrict__ W2,
               const float* __restrict__ b2, float* __restrict__ logits){
  __shared__ float smem[2][CK_ * 128];   // 2 x 32 KB
  const int l   = threadIdx.x & 63;
  const int w   = threadIdx.x >> 6;
  const int colBase = blockIdx.x * 128;
  const int sb8 = __builtin_amdgcn_readfirstlane(w * 8);
  const float* __restrict__ hrow = hT + sb8;

  float acc[8][2];
  #pragma unroll
  for (int i = 0; i < 8; ++i){ acc[i][0] = 0.f; acc[i][1] = 0.f; }

  // stage chunk c into buffer bf: rows c*64..c*64+63 of the 128-col stripe
  auto stage = [&](int c, int bf){
    const float* gbase = W2 + (size_t)(c * CK_ + w * 16 + (l >> 5)) * NC_
                            + colBase + (l & 31) * 4;
    float* lbase = &smem[bf][(w * 16) * 128];
    #pragma unroll
    for (int i = 0; i < 8; ++i)
      gload_lds16(gbase + (size_t)(i * 2) * NC_, lbase + i * 2 * 128);
  };

  stage(0, 0);
  __syncthreads();                       // implicit vmcnt(0) drain
  int bf = 0;
  for (int c = 0; c < (HDIM_ / CK_); ++c){
    if (c < (HDIM_ / CK_) - 1) stage(c + 1, bf ^ 1);
    const float* hk = hrow + (size_t)(c * CK_) * B_;
    #pragma unroll 8
    for (int kk = 0; kk < CK_; ++kk){
      const float w0 = smem[bf][kk * 128 + l];
      const float w1 = smem[bf][kk * 128 + 64 + l];
      const float4 h0 = *reinterpret_cast<const float4*>(hk + (size_t)kk * B_);
      const float4 h1 = *reinterpret_cast<const float4*>(hk + (size_t)kk * B_ + 4);
      acc[0][0] = fmaf(h0.x, w0, acc[0][0]); acc[0][1] = fmaf(h0.x, w1, acc[0][1]);
      acc[1][0] = fmaf(h0.y, w0, acc[1][0]); acc[1][1] = fmaf(h0.y, w1, acc[1][1]);
      acc[2][0] = fmaf(h0.z, w0, acc[2][0]); acc[2][1] = fmaf(h0.z, w1, acc[2][1]);
      acc[3][0] = fmaf(h0.w, w0, acc[3][0]); acc[3][1] = fmaf(h0.w, w1, acc[3][1]);
      acc[4][0] = fmaf(h1.x, w0, acc[4][0]); acc[4][1] = fmaf(h1.x, w1, acc[4][1]);
      acc[5][0] = fmaf(h1.y, w0, acc[5][0]); acc[5][1] = fmaf(h1.y, w1, acc[5][1]);
      acc[6][0] = fmaf(h1.z, w0, acc[6][0]); acc[6][1] = fmaf(h1.z, w1, acc[6][1]);
      acc[7][0] = fmaf(h1.w, w0, acc[7][0]); acc[7][1] = fmaf(h1.w, w1, acc[7][1]);
    }
    __syncthreads();                     // drain stage(c+1) + protect buffer reuse
    bf ^= 1;
  }

  const float bb0 = b2[colBase + l];
  const float bb1 = b2[colBase + 64 + l];
  #pragma unroll
  for (int r = 0; r < 8; ++r){
    logits[(size_t)(sb8 + r) * NC_ + colBase + l]      = acc[r][0] + bb0;
    logits[(size_t)(sb8 + r) * NC_ + colBase + 64 + l] = acc[r][1] + bb1;
  }
}

// K4: per-(row, 8192-col segment) top-10.  grid 256 = 32 rows x 8 segments.
__global__ __launch_bounds__(256)
void topk_seg(const float* __restrict__ logits, float* __restrict__ segv,
              int* __restrict__ segi){
  __shared__ unsigned long long sm[4];
  const int b   = blockIdx.x >> 3;
  const int seg = blockIdx.x & 7;
  const int tid = threadIdx.x;
  const float* row = logits + (size_t)b * NC_ + seg * 8192;
  float v[10]; int ix[10];
  #pragma unroll
  for (int r = 0; r < 10; ++r){ v[r] = -INFINITY; ix[r] = -1; }
  for (int s = 0; s < 32; ++s){
    const int j = s * 256 + tid;
    const float x = row[j];
    if (x > v[9]){
      v[9] = x; ix[9] = seg * 8192 + j;
      #pragma unroll
      for (int p = 9; p > 0; --p){
        if (v[p] > v[p-1]){
          float tv = v[p]; v[p] = v[p-1]; v[p-1] = tv;
          int   ti = ix[p]; ix[p] = ix[p-1]; ix[p-1] = ti;
        }
      }
    }
  }
  for (int r = 0; r < 10; ++r){
    unsigned long long mp = (ix[0] >= 0) ? packv(v[0], ix[0]) : 0ULL;
    unsigned long long g  = block_max_u64(mp, sm, 4);
    if (mp == g && mp != 0ULL){
      #pragma unroll
      for (int q = 0; q < 9; ++q){ v[q] = v[q+1]; ix[q] = ix[q+1]; }
      v[9] = -INFINITY; ix[9] = -1;
    }
    if (tid == 0){
      segv[blockIdx.x * 10 + r] = unpack_val(g);
      segi[blockIdx.x * 10 + r] = unpack_col(g);
    }
  }
}

// K5: merge 8 segment top-10s -> global top-10 per row. grid 32 x 128 thr.
__global__ __launch_bounds__(128)
void topk_merge(const float* __restrict__ segv, const int* __restrict__ segi,
                int* __restrict__ tk_idx, float* __restrict__ tk_score){
  __shared__ unsigned long long sm[2];
  const int b   = blockIdx.x;
  const int tid = threadIdx.x;
  unsigned long long mp = 0ULL;
  if (tid < 80) mp = packv(segv[b * 80 + tid], segi[b * 80 + tid]);
  for (int r = 0; r < 10; ++r){
    unsigned long long g = block_max_u64(mp, sm, 2);
    if (mp == g && mp != 0ULL) mp = 0ULL;   // consumed
    if (tid == 0){
      tk_idx[b * TOPK_ + r]   = unpack_col(g);
      tk_score[b * TOPK_ + r] = 1.0f / (1.0f + expf(-unpack_val(g)));
    }
  }
}

// K6: candidate gather + dot + outputs. d_out: [cands f32][cscores bf16][comb bf16]
__global__ __launch_bounds__(256)
void cand_kernel(const int* __restrict__ gy, const float* __restrict__ embed,
                 const float* __restrict__ h_ext, const int* __restrict__ tk_idx,
                 const float* __restrict__ tk_score, float* __restrict__ out_f){
  const int wid  = threadIdx.x >> 6;
  const int lane = threadIdx.x & 63;
  const int gw   = blockIdx.x * 4 + wid;
  const int b    = gw / CAND_;
  const int c    = gw - b * CAND_;
  const int t    = c / MAXG_;
  const int g    = c - t * MAXG_;

  const unsigned int* gyw = (const unsigned int*)gy;
  const unsigned int probe = gyw[2 * (size_t)(gw * 64 + lane) + 1];
  const bool is64 = (__ballot(probe != 0u) == 0ULL);   // int64 vs int32 group_y layout

  const int idx  = tk_idx[b * TOPK_ + t];
  const size_t li = (size_t)idx * MAXG_ + g;
  const int cand = is64 ? (int)((const long long*)gy)[li] : gy[li];

  const float* erow = embed + (size_t)cand * HDIM_;
  const float* hrow = h_ext + (size_t)b * HDIM_;
  const float4 e0 = reinterpret_cast<const float4*>(erow)[lane];
  const float4 e1 = reinterpret_cast<const float4*>(erow)[lane + 64];
  const float4 h0 = reinterpret_cast<const float4*>(hrow)[lane];
  const float4 h1 = reinterpret_cast<const float4*>(hrow)[lane + 64];
  float s = e0.x*h0.x + e0.y*h0.y + e0.z*h0.z + e0.w*h0.w
          + e1.x*h1.x + e1.y*h1.y + e1.z*h1.z + e1.w*h1.w;
  #pragma unroll
  for (int off = 1; off < 64; off <<= 1) s += __shfl_xor(s, off);
  if (lane == 0){
    const float cs   = (s == 0.0f) ? 0.0f : 1.0f / (1.0f + expf(-s));
    const float comb = cs * ((cand != NL_) ? tk_score[b * TOPK_ + t] : 0.0f);
    const int o = b * CAND_ + c;
    __hip_bfloat16* outs = (__hip_bfloat16*)(out_f + NOUT_);
    __hip_bfloat16* outm = outs + NOUT_;
    out_f[o] = (float)cand;
    outs[o]  = __float2bfloat16(cs);
    outm[o]  = __float2bfloat16(comb);
  }
}

extern "C" void kernel_launch(void* const* d_in, const int* in_sizes, int n_in,
                              void* d_out, int out_size, void* d_ws, size_t ws_size,
                              hipStream_t stream){
  const float* hidf  = (const float*)d_in[0];
  const float* hidl5 = (const float*)d_in[1];
  const float* W1    = (const float*)d_in[2];
  const float* b1    = (const float*)d_in[3];
  const float* W2    = (const float*)d_in[4];
  const float* b2    = (const float*)d_in[5];
  const float* Wext  = (const float*)d_in[6];
  const float* bext  = (const float*)d_in[7];
  const float* embed = (const float*)d_in[8];
  const int*   gy    = (const int*)d_in[9];
  float* out_f = (float*)d_out;

  float* ws      = (float*)d_ws;
  float* logits  = ws;                          // [32][65536] f32 (8 MiB)
  float* partial = ws;                          // aliased: dead before meta_gemm runs
  float* hT      = logits + (size_t)B_ * NC_;   // [512][32]
  float* h_ext   = hT + B_ * HDIM_;             // [32][512]
  float* segv    = h_ext + B_ * HDIM_;          // 2560
  int*   segi    = (int*)(segv + 2560);         // 2560
  float* tk_sc   = (float*)(segi + 2560);       // 320
  int*   tk_ix   = (int*)(tk_sc + 320);         // 320

  mlp_partial<<<dim3(8, 16), 256, 0, stream>>>(hidf, hidl5, W1, Wext, partial);
  act_kernel <<<128, 256, 0, stream>>>(partial, b1, bext, hT, h_ext);
  meta_gemm  <<<NC_ / 128, 256, 0, stream>>>(hT, W2, b2, logits);
  topk_seg   <<<B_ * 8, 256, 0, stream>>>(logits, segv, segi);
  topk_merge <<<B_, 128, 0, stream>>>(segv, segi, tk_ix, tk_sc);
  cand_kernel<<<NOUT_ / 4, 256, 0, stream>>>(gy, embed, h_ext, tk_ix, tk_sc, out_f);
}